// Round 2
// baseline (49737.689 us; speedup 1.0000x reference)
//
#include <hip/hip_runtime.h>

// Fused LSTM, single persistent cooperative kernel, 256 blocks x 512 threads
// (1 block/CU). No precompute phase: Wh/Wx/Wd slices live in REGISTERS per
// thread for the whole kernel (immune to the per-step cache invalidation the
// grid barrier requires). Per timestep:
//   critical : stage h_{t-1} (16KB -> LDS), z_h = h@Wh (256 FMA/thr, broadcast
//              LDS reads), reduce + gates + cell update, write h_t
//   arrive   : per-batch-group barrier (64 blocks)
//   overlap  : z_x(t+1) = x_{t+1}@Wx (global loads, h-independent) and
//              out(t-1) = h_{t-1}@Wd + bd  -- both hidden under barrier wait
//   wait
//
// Decomposition: bid -> cg = bid&63 (8 h-cols j0=8*cg, 8 out-cols), bg = bid>>6
// (8 batch rows b0=8*bg). Thread roles: z: (kr=tid>>5 in 0..15 -> 32-k slice,
// lc=tid&31 -> gate g=lc>>3, col j0+(lc&7)); out: (kr2=(tid>>3)&63, oc=tid&7).
//
// ws: [0,4096) barrier (4 groups, 256B apart); [4096, 4096+131072) h double
// buffer [2][32][512]. Both memset to 0 each launch (h_{-1}=0, c_0=0 in regs).

#define NBLK 256
#define NTHR 512
#define SLEN 1024
#define NBAT 32
#define HID  512
#define GDIM 2048
#define ODIM 512
#define IDIM 512

__device__ __forceinline__ float fsig(float x) { return 1.0f / (1.0f + __expf(-x)); }
__device__ __forceinline__ float ftanh(float x) {
  float xc = fminf(fmaxf(x, -15.0f), 15.0f);
  float e = __expf(2.0f * xc);
  return (e - 1.0f) / (e + 1.0f);
}

// Sense-reversing generation barrier, agent scope. Release: syncthreads drains
// each wave's stores to L2, thread0's __threadfence() writes back L2 (wbl2)
// before the arrive RMW. Acquire: after observing gen, __threadfence()
// invalidates L1/L2 so fresh h is read (weights are in registers -> immune).
__device__ __forceinline__ unsigned bar_arrive(unsigned* gen, unsigned* cnt, unsigned n) {
  __syncthreads();
  unsigned g = 0;
  if (threadIdx.x == 0) {
    __threadfence();
    g = __hip_atomic_load(gen, __ATOMIC_RELAXED, __HIP_MEMORY_SCOPE_AGENT);
    unsigned a = __hip_atomic_fetch_add(cnt, 1u, __ATOMIC_ACQ_REL, __HIP_MEMORY_SCOPE_AGENT);
    if (a == n - 1u) {
      __hip_atomic_store(cnt, 0u, __ATOMIC_RELAXED, __HIP_MEMORY_SCOPE_AGENT);
      __hip_atomic_fetch_add(gen, 1u, __ATOMIC_RELEASE, __HIP_MEMORY_SCOPE_AGENT);
    }
  }
  return g;  // meaningful on thread 0 only
}

__device__ __forceinline__ void bar_wait(unsigned* gen, unsigned g) {
  if (threadIdx.x == 0) {
    while (__hip_atomic_load(gen, __ATOMIC_RELAXED, __HIP_MEMORY_SCOPE_AGENT) == g)
      __builtin_amdgcn_s_sleep(1);
  }
  __syncthreads();
  __threadfence();
}

__global__ __launch_bounds__(NTHR, 2) void lstm_fused(
    const float* __restrict__ x, const float* __restrict__ Wx,
    const float* __restrict__ Wh, const float* __restrict__ bvec,
    const float* __restrict__ Wd, const float* __restrict__ bdvec,
    float* __restrict__ out, float* __restrict__ ws) {
  const int tid = threadIdx.x;
  const int bid = blockIdx.x;
  const int cg = bid & 63;   // same-cg blocks are 64 apart -> same XCD (if %8 map)
  const int bg = bid >> 6;
  const int b0 = bg * 8;
  const int j0 = cg * 8;
  const int o0 = cg * 8;

  unsigned* bar = (unsigned*)ws;
  unsigned* gen = bar + bg * 64;        // 256 B apart per group
  unsigned* cnt = bar + bg * 64 + 16;   // 64 B from gen
  float* hbuf = ws + 1024;              // byte 4096: [2][32][512]

  // z roles
  const int lc = tid & 31;              // local gate col: gate g=lc>>3, jj=lc&7
  const int kr = tid >> 5;              // 0..15 -> k slice [kr*32, +32)
  const int gcol = (lc >> 3) * HID + j0 + (lc & 7);
  // out-proj roles
  const int oc = tid & 7;
  const int kr2 = (tid >> 3) & 63;      // 0..63 -> k slice [kr2*8, +8)
  // h/x staging roles
  const int srow = tid >> 6;            // 0..7
  const int sc8 = (tid & 63) * 8;

  __shared__ float h_lds[8 * HID];      // 16 KB, h_{t-1} rows b0..b0+7
  __shared__ float u16k[4096];          // 16 KB union: z[8][16][32] (critical)
                                        //              opart[8][64][8] (overlap)
  __shared__ float zx_lds[4096];        // 16 KB: zx[8][16][32] (overlap)
  __shared__ float redx_lds[32 * 8];    // [lc][b] reduced x-projection (+bias)
  __shared__ float gs_lds[32 * 8];      // [lc][b] gate sums
  __shared__ float s_lds[4 * 64];       // out-proj stage-2 partials

  // ---- persistent weight registers ----
  float wreg[32], wxreg[32], wdreg[8];
#pragma unroll
  for (int i = 0; i < 32; ++i) wreg[i] = Wh[(size_t)(kr * 32 + i) * GDIM + gcol];
#pragma unroll
  for (int i = 0; i < 32; ++i) wxreg[i] = Wx[(size_t)(kr * 32 + i) * GDIM + gcol];
#pragma unroll
  for (int i = 0; i < 8; ++i) wdreg[i] = Wd[(size_t)(kr2 * 8 + i) * ODIM + o0 + oc];
  const float breg = bvec[gcol];                 // used by reducer threads (tid<256, lc==lc2)
  const float bdreg = bdvec[o0 + oc];            // used by final store threads (tid<64)

  float c_reg = 0.0f;  // cell state of (b0 + tid>>3, j0 + (tid&7)); live for tid<64

  // ---- prologue: z_x for t=0 -> redx ----
  {
    float accx[8];
#pragma unroll
    for (int b = 0; b < 8; ++b) accx[b] = 0.0f;
    const float* xb = x + (size_t)0 * IDIM + kr * 32;
#pragma unroll
    for (int kb = 0; kb < 8; ++kb) {
#pragma unroll
      for (int b = 0; b < 8; ++b) {
        const float4 x4 = *(const float4*)(xb + (size_t)(b0 + b) * SLEN * IDIM + kb * 4);
        accx[b] = fmaf(wxreg[kb * 4 + 0], x4.x, accx[b]);
        accx[b] = fmaf(wxreg[kb * 4 + 1], x4.y, accx[b]);
        accx[b] = fmaf(wxreg[kb * 4 + 2], x4.z, accx[b]);
        accx[b] = fmaf(wxreg[kb * 4 + 3], x4.w, accx[b]);
      }
    }
#pragma unroll
    for (int b = 0; b < 8; ++b) zx_lds[(b * 16 + kr) * 32 + lc] = accx[b];
  }
  __syncthreads();
  if (tid < 256) {
    const int lc2 = tid & 31, b2 = tid >> 5;
    float s = breg;
#pragma unroll
    for (int k = 0; k < 16; ++k) s += zx_lds[(b2 * 16 + k) * 32 + lc2];
    redx_lds[lc2 * 8 + b2] = s;
  }
  __syncthreads();

  // ---- scan ----
  for (int t = 0; t < SLEN; ++t) {
    // ===== critical phase (needs h_{t-1}) =====
    {
      const float* src = hbuf + ((size_t)(t & 1) * NBAT + b0 + srow) * HID + sc8;
      const float4 a = *(const float4*)(src);
      const float4 b = *(const float4*)(src + 4);
      *(float4*)&h_lds[srow * HID + sc8] = a;
      *(float4*)&h_lds[srow * HID + sc8 + 4] = b;
    }
    __syncthreads();
    {
      float acc[8];
#pragma unroll
      for (int b = 0; b < 8; ++b) acc[b] = 0.0f;
#pragma unroll
      for (int kb = 0; kb < 8; ++kb) {
#pragma unroll
        for (int b = 0; b < 8; ++b) {
          const float4 h4 = *(const float4*)&h_lds[b * HID + kr * 32 + kb * 4];
          acc[b] = fmaf(wreg[kb * 4 + 0], h4.x, acc[b]);
          acc[b] = fmaf(wreg[kb * 4 + 1], h4.y, acc[b]);
          acc[b] = fmaf(wreg[kb * 4 + 2], h4.z, acc[b]);
          acc[b] = fmaf(wreg[kb * 4 + 3], h4.w, acc[b]);
        }
      }
#pragma unroll
      for (int b = 0; b < 8; ++b) u16k[(b * 16 + kr) * 32 + lc] = acc[b];
    }
    __syncthreads();
    if (tid < 256) {
      const int lc2 = tid & 31, b2 = tid >> 5;
      float s = redx_lds[lc2 * 8 + b2];
#pragma unroll
      for (int k = 0; k < 16; ++k) s += u16k[(b2 * 16 + k) * 32 + lc2];
      gs_lds[lc2 * 8 + b2] = s;
    }
    __syncthreads();
    if (tid < 64) {
      const int b_l = tid >> 3, j = tid & 7;
      const float zi = gs_lds[(0 * 8 + j) * 8 + b_l];
      const float zf = gs_lds[(1 * 8 + j) * 8 + b_l];
      const float zg = gs_lds[(2 * 8 + j) * 8 + b_l];
      const float zo = gs_lds[(3 * 8 + j) * 8 + b_l];
      const float cn = fsig(zf) * c_reg + fsig(zi) * ftanh(zg);
      c_reg = cn;
      const float hn = fsig(zo) * ftanh(cn);
      hbuf[((size_t)((t + 1) & 1) * NBAT + b0 + b_l) * HID + j0 + j] = hn;
    }
    const unsigned g = bar_arrive(gen, cnt, 64);

    // ===== overlap zone (h-independent; hides barrier wait) =====
    if (t + 1 < SLEN) {  // z_x for t+1 (x from global; half-wave-uniform addrs)
      float accx[8];
#pragma unroll
      for (int b = 0; b < 8; ++b) accx[b] = 0.0f;
      const float* xb = x + (size_t)(t + 1) * IDIM + kr * 32;
#pragma unroll
      for (int kb = 0; kb < 8; ++kb) {
#pragma unroll
        for (int b = 0; b < 8; ++b) {
          const float4 x4 = *(const float4*)(xb + (size_t)(b0 + b) * SLEN * IDIM + kb * 4);
          accx[b] = fmaf(wxreg[kb * 4 + 0], x4.x, accx[b]);
          accx[b] = fmaf(wxreg[kb * 4 + 1], x4.y, accx[b]);
          accx[b] = fmaf(wxreg[kb * 4 + 2], x4.z, accx[b]);
          accx[b] = fmaf(wxreg[kb * 4 + 3], x4.w, accx[b]);
        }
      }
#pragma unroll
      for (int b = 0; b < 8; ++b) zx_lds[(b * 16 + kr) * 32 + lc] = accx[b];
    }
    if (t > 0) {  // out-proj partials for t-1 (h_lds still holds h_{t-1})
      const int kb2 = kr2 * 8;
#pragma unroll
      for (int b = 0; b < 8; ++b) {
        const float4 ha = *(const float4*)&h_lds[b * HID + kb2];
        const float4 hb = *(const float4*)&h_lds[b * HID + kb2 + 4];
        float a = wdreg[0] * ha.x;
        a = fmaf(wdreg[1], ha.y, a);
        a = fmaf(wdreg[2], ha.z, a);
        a = fmaf(wdreg[3], ha.w, a);
        a = fmaf(wdreg[4], hb.x, a);
        a = fmaf(wdreg[5], hb.y, a);
        a = fmaf(wdreg[6], hb.z, a);
        a = fmaf(wdreg[7], hb.w, a);
        u16k[(b * 64 + kr2) * 8 + oc] = a;  // z region is dead here
      }
    }
    __syncthreads();
    if (tid < 256) {
      if (t > 0) {  // out-proj stage 1 (interleaved q -> conflict-free)
        const int q = tid & 3, oc2 = (tid >> 2) & 7, b2 = tid >> 5;
        float s = 0.0f;
#pragma unroll
        for (int k2 = 0; k2 < 16; ++k2) s += u16k[(b2 * 64 + q + 4 * k2) * 8 + oc2];
        s_lds[q * 64 + b2 * 8 + oc2] = s;
      }
      if (t + 1 < SLEN) {  // reduce z_x -> redx (read in next critical phase)
        const int lc2 = tid & 31, b2 = tid >> 5;
        float s = breg;
#pragma unroll
        for (int k = 0; k < 16; ++k) s += zx_lds[(b2 * 16 + k) * 32 + lc2];
        redx_lds[lc2 * 8 + b2] = s;
      }
    }
    __syncthreads();
    if (t > 0 && tid < 64) {
      const int b_l = tid >> 3, oo = tid & 7;
      const float s = s_lds[tid] + s_lds[64 + tid] + s_lds[128 + tid] + s_lds[192 + tid] + bdreg;
      out[((size_t)(b0 + b_l) * SLEN + (t - 1)) * ODIM + o0 + oo] = s;
    }
    bar_wait(gen, g);
  }

  // ---- epilogue: out row SLEN-1 from h_{SLEN-1} (in hbuf[(SLEN)&1 == 0]) ----
  {
    const float* src = hbuf + ((size_t)(SLEN & 1) * NBAT + b0 + srow) * HID + sc8;
    const float4 a = *(const float4*)(src);
    const float4 b = *(const float4*)(src + 4);
    *(float4*)&h_lds[srow * HID + sc8] = a;
    *(float4*)&h_lds[srow * HID + sc8 + 4] = b;
  }
  __syncthreads();
  {
    const int kb2 = kr2 * 8;
#pragma unroll
    for (int b = 0; b < 8; ++b) {
      const float4 ha = *(const float4*)&h_lds[b * HID + kb2];
      const float4 hb = *(const float4*)&h_lds[b * HID + kb2 + 4];
      float a = wdreg[0] * ha.x;
      a = fmaf(wdreg[1], ha.y, a);
      a = fmaf(wdreg[2], ha.z, a);
      a = fmaf(wdreg[3], ha.w, a);
      a = fmaf(wdreg[4], hb.x, a);
      a = fmaf(wdreg[5], hb.y, a);
      a = fmaf(wdreg[6], hb.z, a);
      a = fmaf(wdreg[7], hb.w, a);
      u16k[(b * 64 + kr2) * 8 + oc] = a;
    }
  }
  __syncthreads();
  if (tid < 256) {
    const int q = tid & 3, oc2 = (tid >> 2) & 7, b2 = tid >> 5;
    float s = 0.0f;
#pragma unroll
    for (int k2 = 0; k2 < 16; ++k2) s += u16k[(b2 * 64 + q + 4 * k2) * 8 + oc2];
    s_lds[q * 64 + b2 * 8 + oc2] = s;
  }
  __syncthreads();
  if (tid < 64) {
    const int b_l = tid >> 3, oo = tid & 7;
    const float s = s_lds[tid] + s_lds[64 + tid] + s_lds[128 + tid] + s_lds[192 + tid] + bdreg;
    out[((size_t)(b0 + b_l) * SLEN + (SLEN - 1)) * ODIM + o0 + oo] = s;
  }
}

extern "C" void kernel_launch(void* const* d_in, const int* in_sizes, int n_in,
                              void* d_out, int out_size, void* d_ws, size_t ws_size,
                              hipStream_t stream) {
  const float* x  = (const float*)d_in[0];
  const float* Wx = (const float*)d_in[1];
  const float* Wh = (const float*)d_in[2];
  const float* bv = (const float*)d_in[3];
  const float* Wd = (const float*)d_in[4];
  const float* bd = (const float*)d_in[5];
  float* out = (float*)d_out;
  float* ws  = (float*)d_ws;

  // barrier (4 KB) + h double buffer (128 KB) -> zero every call
  hipMemsetAsync(d_ws, 0, 4096 + (size_t)2 * NBAT * HID * sizeof(float), stream);

  void* args[] = {(void*)&x, (void*)&Wx, (void*)&Wh, (void*)&bv,
                  (void*)&Wd, (void*)&bd, (void*)&out, (void*)&ws};
  hipLaunchCooperativeKernel((void*)lstm_fused, dim3(NBLK), dim3(NTHR), args, 0u, stream);
}

// Round 3
// 7976.903 us; speedup vs baseline: 6.2352x; 6.2352x over previous
//
#include <hip/hip_runtime.h>

// Fused LSTM, persistent cooperative kernel, 256 blocks x 512 threads.
// Round-3 change: NO __threadfence anywhere (r2 post-mortem: agent fences =
// buffer_wbl2/buffer_inv full-L2 scans ~46us/step, VALUBusy 4.5%). Cross-block
// h exchange + barrier flags go through SYSTEM-scope relaxed atomics (sc0 sc1,
// bypass L1/L2, served at the coherence point / Infinity Cache). Everything
// else (x, Wd, out, weights) stays normally cached and never invalidated.
//
// Sync protocol per step t (per bg-group of 64 blocks):
//   writer: gates -> 64 sc-stores of h_t (coalesced 256B) -> s_waitcnt vmcnt(0)
//           -> flag[bid] = t+1 (sc store)
//   reader (next iter top): each wave polls the 8 producer flags of its slice
//           (>= t), then sc-loads the slice -> LDS. Stage-sync joins waves.
// Safety: flag=t+1 is posted only after ALL our waves finished stage-reading
// buffer parity (t&1) (full-block syncthreads precede gates), so a peer that
// observed all flags >= t+1 may overwrite parity ((t+2)&1 == t&1).
//
// ws: [0,4096) flags (256 u32, flag[bid]); [4096, 135168) hpack
//     [2][4][64][64] f32 = [parity][bg][cg][b_l*8+j]. memset 0 per launch.

#define NBLK 256
#define NTHR 512
#define SLEN 1024
#define NBAT 32
#define HID  512
#define GDIM 2048
#define ODIM 512
#define IDIM 512
#define HSTR 520  // h_lds row stride in floats (512 is bank-aligned -> pad)

typedef unsigned long long u64t;

__device__ __forceinline__ float fsig(float x) { return 1.0f / (1.0f + __expf(-x)); }
__device__ __forceinline__ float ftanh(float x) {
  float xc = fminf(fmaxf(x, -15.0f), 15.0f);
  float e = __expf(2.0f * xc);
  return (e - 1.0f) / (e + 1.0f);
}

__device__ __forceinline__ unsigned ld_flag(const unsigned* p) {
  return __hip_atomic_load(p, __ATOMIC_RELAXED, __HIP_MEMORY_SCOPE_SYSTEM);
}
__device__ __forceinline__ void st_flag(unsigned* p, unsigned v) {
  __hip_atomic_store(p, v, __ATOMIC_RELAXED, __HIP_MEMORY_SCOPE_SYSTEM);
}
__device__ __forceinline__ u64t ld_sys8(const float* p) {
  return __hip_atomic_load((const u64t*)p, __ATOMIC_RELAXED, __HIP_MEMORY_SCOPE_SYSTEM);
}
__device__ __forceinline__ void st_sys4(float* p, float v) {
  __hip_atomic_store((unsigned*)p, __float_as_uint(v), __ATOMIC_RELAXED,
                     __HIP_MEMORY_SCOPE_SYSTEM);
}

__global__ __launch_bounds__(NTHR, 2) void lstm_fused(
    const float* __restrict__ x, const float* __restrict__ Wx,
    const float* __restrict__ Wh, const float* __restrict__ bvec,
    const float* __restrict__ Wd, const float* __restrict__ bdvec,
    float* __restrict__ out, float* __restrict__ ws) {
  const int tid = threadIdx.x;
  const int bid = blockIdx.x;
  const int cg = bid & 63;
  const int bg = bid >> 6;
  const int b0 = bg * 8;
  const int j0 = cg * 8;
  const int o0 = cg * 8;

  unsigned* flags = (unsigned*)ws;       // flag[bid]
  float* hp = ws + 1024;                 // hpack [2][4][64][64]

  // z roles
  const int lc = tid & 31;               // gate g=lc>>3, col j0+(lc&7)
  const int kr = tid >> 5;               // k slice [kr*32, +32)
  const int gcol = (lc >> 3) * HID + j0 + (lc & 7);
  // out-proj roles
  const int oc = tid & 7;
  const int kr2 = (tid >> 3) & 63;       // k slice [kr2*8, +8)

  __shared__ float h_lds[8 * HSTR];      // h_{t-1}, rows b0..b0+7, stride-padded
  __shared__ float u16k[4096];           // union: z[8][16][32] / opart[8][64][8]
  __shared__ float zx_lds[4096];         // zx[8][16][32]
  __shared__ float redx_lds[32 * 8];     // [lc][b] reduced x-proj (+bias)
  __shared__ float gs_lds[32 * 8];       // [lc][b] gate sums
  __shared__ float s_lds[4 * 64];        // out-proj stage-2 partials

  // persistent weight registers
  float wreg[32], wxreg[32], wdreg[8];
#pragma unroll
  for (int i = 0; i < 32; ++i) wreg[i] = Wh[(size_t)(kr * 32 + i) * GDIM + gcol];
#pragma unroll
  for (int i = 0; i < 32; ++i) wxreg[i] = Wx[(size_t)(kr * 32 + i) * GDIM + gcol];
#pragma unroll
  for (int i = 0; i < 8; ++i) wdreg[i] = Wd[(size_t)(kr2 * 8 + i) * ODIM + o0 + oc];
  const float breg = bvec[gcol];
  const float bdreg = bdvec[o0 + oc];

  float c_reg = 0.0f;  // cell state of (b0 + tid>>3, j0 + (tid&7)); tid<64

  // ---- prologue: z_x for t=0 -> redx ----
  {
    float accx[8];
#pragma unroll
    for (int b = 0; b < 8; ++b) accx[b] = 0.0f;
    const float* xb = x + kr * 32;
#pragma unroll
    for (int kb = 0; kb < 8; ++kb) {
#pragma unroll
      for (int b = 0; b < 8; ++b) {
        const float4 x4 = *(const float4*)(xb + (size_t)(b0 + b) * SLEN * IDIM + kb * 4);
        accx[b] = fmaf(wxreg[kb * 4 + 0], x4.x, accx[b]);
        accx[b] = fmaf(wxreg[kb * 4 + 1], x4.y, accx[b]);
        accx[b] = fmaf(wxreg[kb * 4 + 2], x4.z, accx[b]);
        accx[b] = fmaf(wxreg[kb * 4 + 3], x4.w, accx[b]);
      }
    }
#pragma unroll
    for (int b = 0; b < 8; ++b) zx_lds[(b * 16 + kr) * 32 + lc] = accx[b];
  }
  __syncthreads();
  if (tid < 256) {
    const int lc2 = tid & 31, b2 = tid >> 5;
    float s = breg;
#pragma unroll
    for (int k = 0; k < 16; ++k) s += zx_lds[(b2 * 16 + k) * 32 + lc2];
    redx_lds[lc2 * 8 + b2] = s;
  }
  __syncthreads();

  // ---- scan ----
  for (int t = 0; t < SLEN; ++t) {
    // fused wait+stage: this lane's slice producer is cg' = tid>>3
    {
      const unsigned* fp = flags + bg * 64 + (tid >> 3);
      while (ld_flag(fp) < (unsigned)t) __builtin_amdgcn_s_sleep(1);
      asm volatile("" ::: "memory");  // no hoisting of data loads above poll
      const float* src = hp + ((size_t)((t & 1) * 4 + bg)) * 4096 + tid * 8;
      const u64t v0 = ld_sys8(src + 0);
      const u64t v1 = ld_sys8(src + 2);
      const u64t v2 = ld_sys8(src + 4);
      const u64t v3 = ld_sys8(src + 6);
      float* dst = &h_lds[(tid & 7) * HSTR + (tid >> 3) * 8];
      dst[0] = __uint_as_float((unsigned)v0);
      dst[1] = __uint_as_float((unsigned)(v0 >> 32));
      dst[2] = __uint_as_float((unsigned)v1);
      dst[3] = __uint_as_float((unsigned)(v1 >> 32));
      dst[4] = __uint_as_float((unsigned)v2);
      dst[5] = __uint_as_float((unsigned)(v2 >> 32));
      dst[6] = __uint_as_float((unsigned)v3);
      dst[7] = __uint_as_float((unsigned)(v3 >> 32));
    }
    __syncthreads();

    // z_h = h_{t-1} @ Wh (broadcast LDS reads, weights in regs)
    {
      float acc[8];
#pragma unroll
      for (int b = 0; b < 8; ++b) acc[b] = 0.0f;
#pragma unroll
      for (int kb = 0; kb < 8; ++kb) {
#pragma unroll
        for (int b = 0; b < 8; ++b) {
          const float4 h4 = *(const float4*)&h_lds[b * HSTR + kr * 32 + kb * 4];
          acc[b] = fmaf(wreg[kb * 4 + 0], h4.x, acc[b]);
          acc[b] = fmaf(wreg[kb * 4 + 1], h4.y, acc[b]);
          acc[b] = fmaf(wreg[kb * 4 + 2], h4.z, acc[b]);
          acc[b] = fmaf(wreg[kb * 4 + 3], h4.w, acc[b]);
        }
      }
#pragma unroll
      for (int b = 0; b < 8; ++b) u16k[(b * 16 + kr) * 32 + lc] = acc[b];
    }
    __syncthreads();
    if (tid < 256) {
      const int lc2 = tid & 31, b2 = tid >> 5;
      float s = redx_lds[lc2 * 8 + b2];
#pragma unroll
      for (int k = 0; k < 16; ++k) s += u16k[(b2 * 16 + k) * 32 + lc2];
      gs_lds[lc2 * 8 + b2] = s;
    }
    __syncthreads();

    // gates + cell update + h_t publish (wave 0); other waves go to overlap
    if (tid < 64) {
      const int b_l = tid >> 3, j = tid & 7;
      const float zi = gs_lds[(0 * 8 + j) * 8 + b_l];
      const float zf = gs_lds[(1 * 8 + j) * 8 + b_l];
      const float zg = gs_lds[(2 * 8 + j) * 8 + b_l];
      const float zo = gs_lds[(3 * 8 + j) * 8 + b_l];
      const float cn = fsig(zf) * c_reg + fsig(zi) * ftanh(zg);
      c_reg = cn;
      const float hn = fsig(zo) * ftanh(cn);
      st_sys4(hp + ((size_t)(((t + 1) & 1) * 4 + bg)) * 4096 + cg * 64 + tid, hn);
      asm volatile("s_waitcnt vmcnt(0)" ::: "memory");  // h at coherence point
      if (tid == 0) st_flag(flags + bid, (unsigned)(t + 1));
    }

    // overlap (hidden under peers' latency): z_x(t+1), out-partials(t-1)
    if (t + 1 < SLEN) {
      float accx[8];
#pragma unroll
      for (int b = 0; b < 8; ++b) accx[b] = 0.0f;
      const float* xb = x + (size_t)(t + 1) * IDIM + kr * 32;
#pragma unroll
      for (int kb = 0; kb < 8; ++kb) {
#pragma unroll
        for (int b = 0; b < 8; ++b) {
          const float4 x4 = *(const float4*)(xb + (size_t)(b0 + b) * SLEN * IDIM + kb * 4);
          accx[b] = fmaf(wxreg[kb * 4 + 0], x4.x, accx[b]);
          accx[b] = fmaf(wxreg[kb * 4 + 1], x4.y, accx[b]);
          accx[b] = fmaf(wxreg[kb * 4 + 2], x4.z, accx[b]);
          accx[b] = fmaf(wxreg[kb * 4 + 3], x4.w, accx[b]);
        }
      }
#pragma unroll
      for (int b = 0; b < 8; ++b) zx_lds[(b * 16 + kr) * 32 + lc] = accx[b];
    }
    if (t > 0) {  // out-proj partials for t-1 (h_lds == h_{t-1})
      const int kb2 = kr2 * 8;
#pragma unroll
      for (int b = 0; b < 8; ++b) {
        const float4 ha = *(const float4*)&h_lds[b * HSTR + kb2];
        const float4 hb = *(const float4*)&h_lds[b * HSTR + kb2 + 4];
        float a = wdreg[0] * ha.x;
        a = fmaf(wdreg[1], ha.y, a);
        a = fmaf(wdreg[2], ha.z, a);
        a = fmaf(wdreg[3], ha.w, a);
        a = fmaf(wdreg[4], hb.x, a);
        a = fmaf(wdreg[5], hb.y, a);
        a = fmaf(wdreg[6], hb.z, a);
        a = fmaf(wdreg[7], hb.w, a);
        u16k[(b * 64 + kr2) * 8 + oc] = a;
      }
    }
    __syncthreads();
    if (tid < 256) {
      if (t > 0) {
        const int q = tid & 3, oc2 = (tid >> 2) & 7, b2 = tid >> 5;
        float s = 0.0f;
#pragma unroll
        for (int k2 = 0; k2 < 16; ++k2) s += u16k[(b2 * 64 + q + 4 * k2) * 8 + oc2];
        s_lds[q * 64 + b2 * 8 + oc2] = s;
      }
      if (t + 1 < SLEN) {
        const int lc2 = tid & 31, b2 = tid >> 5;
        float s = breg;
#pragma unroll
        for (int k = 0; k < 16; ++k) s += zx_lds[(b2 * 16 + k) * 32 + lc2];
        redx_lds[lc2 * 8 + b2] = s;
      }
    }
    __syncthreads();
    if (t > 0 && tid < 64) {
      const int b_l = tid >> 3, oo = tid & 7;
      const float s = s_lds[tid] + s_lds[64 + tid] + s_lds[128 + tid] + s_lds[192 + tid] + bdreg;
      out[((size_t)(b0 + b_l) * SLEN + (t - 1)) * ODIM + o0 + oo] = s;
    }
  }

  // ---- epilogue: out row SLEN-1 from h_{SLEN-1} (parity 0) ----
  {
    const unsigned* fp = flags + bg * 64 + (tid >> 3);
    while (ld_flag(fp) < (unsigned)SLEN) __builtin_amdgcn_s_sleep(1);
    asm volatile("" ::: "memory");
    const float* src = hp + ((size_t)((SLEN & 1) * 4 + bg)) * 4096 + tid * 8;
    const u64t v0 = ld_sys8(src + 0);
    const u64t v1 = ld_sys8(src + 2);
    const u64t v2 = ld_sys8(src + 4);
    const u64t v3 = ld_sys8(src + 6);
    float* dst = &h_lds[(tid & 7) * HSTR + (tid >> 3) * 8];
    dst[0] = __uint_as_float((unsigned)v0);
    dst[1] = __uint_as_float((unsigned)(v0 >> 32));
    dst[2] = __uint_as_float((unsigned)v1);
    dst[3] = __uint_as_float((unsigned)(v1 >> 32));
    dst[4] = __uint_as_float((unsigned)v2);
    dst[5] = __uint_as_float((unsigned)(v2 >> 32));
    dst[6] = __uint_as_float((unsigned)v3);
    dst[7] = __uint_as_float((unsigned)(v3 >> 32));
  }
  __syncthreads();
  {
    const int kb2 = kr2 * 8;
#pragma unroll
    for (int b = 0; b < 8; ++b) {
      const float4 ha = *(const float4*)&h_lds[b * HSTR + kb2];
      const float4 hb = *(const float4*)&h_lds[b * HSTR + kb2 + 4];
      float a = wdreg[0] * ha.x;
      a = fmaf(wdreg[1], ha.y, a);
      a = fmaf(wdreg[2], ha.z, a);
      a = fmaf(wdreg[3], ha.w, a);
      a = fmaf(wdreg[4], hb.x, a);
      a = fmaf(wdreg[5], hb.y, a);
      a = fmaf(wdreg[6], hb.z, a);
      a = fmaf(wdreg[7], hb.w, a);
      u16k[(b * 64 + kr2) * 8 + oc] = a;
    }
  }
  __syncthreads();
  if (tid < 256) {
    const int q = tid & 3, oc2 = (tid >> 2) & 7, b2 = tid >> 5;
    float s = 0.0f;
#pragma unroll
    for (int k2 = 0; k2 < 16; ++k2) s += u16k[(b2 * 64 + q + 4 * k2) * 8 + oc2];
    s_lds[q * 64 + b2 * 8 + oc2] = s;
  }
  __syncthreads();
  if (tid < 64) {
    const int b_l = tid >> 3, oo = tid & 7;
    const float s = s_lds[tid] + s_lds[64 + tid] + s_lds[128 + tid] + s_lds[192 + tid] + bdreg;
    out[((size_t)(b0 + b_l) * SLEN + (SLEN - 1)) * ODIM + o0 + oo] = s;
  }
}

extern "C" void kernel_launch(void* const* d_in, const int* in_sizes, int n_in,
                              void* d_out, int out_size, void* d_ws, size_t ws_size,
                              hipStream_t stream) {
  const float* x  = (const float*)d_in[0];
  const float* Wx = (const float*)d_in[1];
  const float* Wh = (const float*)d_in[2];
  const float* bv = (const float*)d_in[3];
  const float* Wd = (const float*)d_in[4];
  const float* bd = (const float*)d_in[5];
  float* out = (float*)d_out;
  float* ws  = (float*)d_ws;

  // flags (4 KB) + hpack (128 KB) -> zero every call (h_{-1}=0, flags=0)
  hipMemsetAsync(d_ws, 0, 4096 + (size_t)2 * NBAT * HID * sizeof(float), stream);

  void* args[] = {(void*)&x, (void*)&Wx, (void*)&Wh, (void*)&bv,
                  (void*)&Wd, (void*)&bd, (void*)&out, (void*)&ws};
  hipLaunchCooperativeKernel((void*)lstm_fused, dim3(NBLK), dim3(NTHR), args, 0u, stream);
}